// Round 13
// baseline (1193.622 us; speedup 1.0000x reference)
//
#include <hip/hip_runtime.h>

// ---------------- problem constants ----------------
#define B_  128
#define S_  200
#define F_  32
#define D_  512
#define NH_ 4
#define DH_ 128
#define KK_ 4
#define NB_ 2
#define UP_ 704
#define FD_ 7
#define M_  (B_*S_)   // 25600 rows

typedef unsigned short u16;
typedef _Float16 f16;
typedef __attribute__((ext_vector_type(8))) _Float16 f16x8;
typedef __attribute__((ext_vector_type(8))) short  s16x8;
typedef __attribute__((ext_vector_type(4))) float  f32x4;

__device__ __forceinline__ u16 f2bf(float f){
  unsigned x = __builtin_bit_cast(unsigned, f);
  return (u16)((x + 0x7fffu + ((x>>16)&1u)) >> 16);   // RNE
}
__device__ __forceinline__ float bf2f(u16 u){
  return __builtin_bit_cast(float, (unsigned)u << 16);
}
__device__ __forceinline__ f32x4 mfma16(s16x8 a, s16x8 b, f32x4 c){
  return __builtin_amdgcn_mfma_f32_16x16x32_bf16(a, b, c, 0, 0, 0);
}
__device__ __forceinline__ f32x4 mfma16h(f16x8 a, f16x8 b, f32x4 c){
  return __builtin_amdgcn_mfma_f32_16x16x32_f16(a, b, c, 0, 0, 0);
}
// fast native math (v_exp_f32 / v_log_f32 / v_rcp_f32), rel err ~1e-6
__device__ __forceinline__ float frcp(float x){ return __builtin_amdgcn_rcpf(x); }
__device__ __forceinline__ float tanh_fast(float z){
  const float u = __expf(-2.f*fabsf(z));          // in (0,1]
  const float t = (1.f-u)*frcp(1.f+u);
  return copysignf(t, z);
}
__device__ __forceinline__ float logsig_fast(float f){  // log(sigmoid(f))
  const float t = __expf(-fabsf(f));
  return fminf(f, 0.f) - __logf(1.f + t);
}
__device__ __forceinline__ float sigmoid_fast(float x){
  return frcp(1.f + __expf(-x));
}
// lgkm-only barrier: does NOT drain vmcnt, so global prefetch loads/stores
// stay in flight across it. All cross-wave data moves via LDS.
__device__ __forceinline__ void bar_lgkm(){
  __builtin_amdgcn_sched_barrier(0);
  asm volatile("s_waitcnt lgkmcnt(0)" ::: "memory");
  __builtin_amdgcn_s_barrier();
  __builtin_amdgcn_sched_barrier(0);
}
// 64-lane sum via DPP (VALU pipe, no LDS). ctrl must be immediate -> template.
template<int CTRL>
__device__ __forceinline__ float dpp_add(float v){
  int x = __builtin_amdgcn_update_dpp(0, __builtin_bit_cast(int, v), CTRL, 0xf, 0xf, false);
  return v + __builtin_bit_cast(float, x);
}
__device__ __forceinline__ float wave_sum64(float v){
  v = dpp_add<0x111>(v);   // row_shr:1
  v = dpp_add<0x112>(v);   // row_shr:2
  v = dpp_add<0x114>(v);   // row_shr:4
  v = dpp_add<0x118>(v);   // row_shr:8
  v = dpp_add<0x142>(v);   // row_bcast:15
  v = dpp_add<0x143>(v);   // row_bcast:31
  return __builtin_bit_cast(float, __builtin_amdgcn_readlane(__builtin_bit_cast(int, v), 63));
}

// ---------------- tiny utility kernels ----------------
__global__ void k_zero(float* __restrict__ p, int n){
  int i = blockIdx.x*256 + threadIdx.x;
  if (i < n) p[i] = 0.f;
}
__global__ void k_sentinel(float* __restrict__ out, int n){
  int i = blockIdx.x*256 + threadIdx.x;
  if (i < n) out[i] = -12345.0f;
}

// ---- weight cast+pack kernels: output k-slab fragment order [K/32][N][32] ----
// gates: NB*4*NH matrices of [128][128] -> per-mat [4][128][32]
__global__ void k_cast_pack_gates(const float* __restrict__ in, u16* __restrict__ out, int n){
  int i = blockIdx.x*256 + threadIdx.x;
  if (i >= n) return;
  const int mat = i >> 14;            // /16384
  const int rem = i & 16383;
  const int slab = rem >> 12;         // /(128*32)
  const int r2   = rem & 4095;
  const int nn   = r2 >> 5;
  const int kk   = r2 & 31;
  out[i] = f2bf(in[(size_t)mat*16384 + (size_t)(slab*32 + kk)*DH_ + nn]);
}
// ff_up: [NB][D=512][2UP=1408] -> [NB][16][1408][32], with GLU column interleave:
// packed col n -> src col: j=n&127, t=n>>7; col = j<64 ? t*64+j : UP + t*64 + (j-64)
__global__ void k_cast_pack_up(const float* __restrict__ in, u16* __restrict__ out, int n){
  int i = blockIdx.x*256 + threadIdx.x;
  if (i >= n) return;
  const int per = 512*1408;
  const int blk = i / per;
  const int rem = i - blk*per;
  const int slab = rem / (1408*32);
  const int r2   = rem - slab*(1408*32);
  const int nn   = r2 >> 5;
  const int kk   = r2 & 31;
  const int j = nn & 127, tt = nn >> 7;
  const int col = (j < 64) ? (tt*64 + j) : (UP_ + tt*64 + (j - 64));
  out[i] = f2bf(in[(size_t)(blk*512 + slab*32 + kk)*(2*UP_) + col]);
}
// ff_down: [NB][UP=704][D=512] -> [NB][22][512][32]
__global__ void k_cast_pack_dn(const float* __restrict__ in, u16* __restrict__ out, int n){
  int i = blockIdx.x*256 + threadIdx.x;
  if (i >= n) return;
  const int per = 704*512;
  const int blk = i / per;
  const int rem = i - blk*per;
  const int slab = rem / (512*32);
  const int r2   = rem - slab*(512*32);
  const int nn   = r2 >> 5;
  const int kk   = r2 & 31;
  out[i] = f2bf(in[(size_t)(blk*704 + slab*32 + kk)*D_ + nn]);
}

// ---------------- input projection: h = x @ w_in + b_in ----------------
__global__ __launch_bounds__(256) void k_inproj(const float* __restrict__ x,
    const float* __restrict__ w, const float* __restrict__ bias, float* __restrict__ h)
{
  __shared__ float xs[8][32];
  const int m0 = blockIdx.x*8, tid = threadIdx.x;
  xs[tid>>5][tid&31] = x[(size_t)(m0 + (tid>>5))*F_ + (tid&31)];
  __syncthreads();
  #pragma unroll
  for (int hf=0; hf<2; ++hf){
    const int e = tid + hf*256;
    float a[8];
    const float bb = bias[e];
    #pragma unroll
    for (int r=0;r<8;r++) a[r]=bb;
    for (int f=0; f<F_; ++f){
      const float wv = w[(size_t)f*D_ + e];
      #pragma unroll
      for (int r=0;r<8;r++) a[r] += xs[r][f]*wv;
    }
    #pragma unroll
    for (int r=0;r<8;r++) h[(size_t)(m0+r)*D_ + e] = a[r];
  }
}

// ---------------- LayerNorm over D=512 -> bf16 ----------------
__global__ __launch_bounds__(128) void k_ln(const float* __restrict__ in, const float* __restrict__ w,
      u16* __restrict__ outb)
{
  const int row = blockIdx.x, tid = threadIdx.x;
  const f32x4* rp = (const f32x4*)(in + (size_t)row*D_);
  f32x4 v = rp[tid];
  float s = v[0]+v[1]+v[2]+v[3];
  float q = v[0]*v[0]+v[1]*v[1]+v[2]*v[2]+v[3]*v[3];
  #pragma unroll
  for (int off=32; off; off>>=1){ s += __shfl_down(s,off,64); q += __shfl_down(q,off,64); }
  __shared__ float red[2][2];
  if ((tid&63)==0){ red[tid>>6][0]=s; red[tid>>6][1]=q; }
  __syncthreads();
  const float sum = red[0][0]+red[1][0], sq = red[0][1]+red[1][1];
  const float mu  = sum*(1.f/D_);
  const float var = sq*(1.f/D_) - mu*mu;
  const float inv = rsqrtf(var + 1e-5f);
  f32x4 wv = ((const f32x4*)w)[tid];
  ushort4 ob;
  ob.x=f2bf((v[0]-mu)*inv*wv[0]); ob.y=f2bf((v[1]-mu)*inv*wv[1]);
  ob.z=f2bf((v[2]-mu)*inv*wv[2]); ob.w=f2bf((v[3]-mu)*inv*wv[3]);
  ((ushort4*)(outb + (size_t)row*D_))[tid] = ob;
}

// ---------------- fused residual add + LayerNorm: h += y(bf16); out = LN(h) ----------------
__global__ __launch_bounds__(128) void k_addln(float* __restrict__ h, const u16* __restrict__ y,
      const float* __restrict__ w, u16* __restrict__ outb)
{
  const int row = blockIdx.x, tid = threadIdx.x;
  f32x4 v = ((const f32x4*)(h + (size_t)row*D_))[tid];
  ushort4 yq = ((const ushort4*)(y + (size_t)row*D_))[tid];
  v[0]+=bf2f(yq.x); v[1]+=bf2f(yq.y); v[2]+=bf2f(yq.z); v[3]+=bf2f(yq.w);
  ((f32x4*)(h + (size_t)row*D_))[tid] = v;
  float s = v[0]+v[1]+v[2]+v[3];
  float q = v[0]*v[0]+v[1]*v[1]+v[2]*v[2]+v[3]*v[3];
  #pragma unroll
  for (int off=32; off; off>>=1){ s += __shfl_down(s,off,64); q += __shfl_down(q,off,64); }
  __shared__ float red[2][2];
  if ((tid&63)==0){ red[tid>>6][0]=s; red[tid>>6][1]=q; }
  __syncthreads();
  const float sum = red[0][0]+red[1][0], sq = red[0][1]+red[1][1];
  const float mu  = sum*(1.f/D_);
  const float var = sq*(1.f/D_) - mu*mu;
  const float inv = rsqrtf(var + 1e-5f);
  f32x4 wv = ((const f32x4*)w)[tid];
  ushort4 ob;
  ob.x=f2bf((v[0]-mu)*inv*wv[0]); ob.y=f2bf((v[1]-mu)*inv*wv[1]);
  ob.z=f2bf((v[2]-mu)*inv*wv[2]); ob.w=f2bf((v[3]-mu)*inv*wv[3]);
  ((ushort4*)(outb + (size_t)row*D_))[tid] = ob;
}

// ---------------- causal depthwise conv (K=4) + SiLU -> bf16, s-chunked ----------------
__global__ void k_conv(const u16* __restrict__ xnbf, const float* __restrict__ cw,
                       const float* __restrict__ cb, u16* __restrict__ xcc,
                       int s0, int Sc)
{
  const int idx = blockIdx.x*256 + threadIdx.x;   // over B*Sc*128 quads
  const int e4 = idx & 127;
  const int sl = (idx >> 7) % Sc;
  const int b  = idx / (128*Sc);
  const int s  = s0 + sl;
  f32x4 acc = ((const f32x4*)cb)[e4];
  #pragma unroll
  for (int k=0;k<KK_;k++){
    const int sp = s - (KK_-1) + k;
    if (sp >= 0){
      f32x4 w4 = ((const f32x4*)cw)[k*128 + e4];
      ushort4 xq = ((const ushort4*)xnbf)[(size_t)(b*S_ + sp)*128 + e4];
      acc[0] += w4[0]*bf2f(xq.x);
      acc[1] += w4[1]*bf2f(xq.y);
      acc[2] += w4[2]*bf2f(xq.z);
      acc[3] += w4[3]*bf2f(xq.w);
    }
  }
  ushort4 o;
  float a;
  a=acc[0]; o.x=f2bf(a*sigmoid_fast(a));
  a=acc[1]; o.y=f2bf(a*sigmoid_fast(a));
  a=acc[2]; o.z=f2bf(a*sigmoid_fast(a));
  a=acc[3]; o.w=f2bf(a*sigmoid_fast(a));
  ((ushort4*)xcc)[idx] = o;
}

// ---------------- bf16 MFMA GEMM (down-proj): C[M,N] += A[M,K] @ Bpacked ----------------
// Bw packed [K/32][N][32]; ldb = N.
__global__ __launch_bounds__(256) void k_gemm_ffn(
    const u16* __restrict__ A, int lda,
    const u16* __restrict__ Bw, int ldb,
    float* __restrict__ C, int ldc,
    int Kdim, int addmode)
{
  __shared__ u16 As[128*40];
  __shared__ u16 Bs[128*40];
  const int tid = threadIdx.x;
  const int m0 = blockIdx.x * 128;
  const int n0 = blockIdx.y * 128;
  const int w = tid >> 6, l = tid & 63;
  const int l16 = l & 15, kg = l >> 4;
  f32x4 acc[2][8];
  #pragma unroll
  for (int i=0;i<2;i++)
    #pragma unroll
    for (int j=0;j<8;j++) acc[i][j] = (f32x4)0.f;
  const int nk = Kdim >> 5;
  for (int kt=0; kt<nk; ++kt){
    const int k0 = kt<<5;
    __syncthreads();
    #pragma unroll
    for (int p=0;p<2;p++){
      const int idx = p*256 + tid;
      const int row = idx>>2, kc = (idx&3)*8;
      s16x8 v = *(const s16x8*)(A + (size_t)(m0+row)*lda + k0 + kc);
      *(s16x8*)&As[row*40 + kc] = v;
    }
    #pragma unroll
    for (int p=0;p<2;p++){
      const int idx = p*256 + tid;
      const int nl = idx>>2, ck = (idx&3)*8;
      s16x8 v = *(const s16x8*)(Bw + (size_t)kt*ldb*32 + (size_t)(n0+nl)*32 + ck);
      *(s16x8*)&Bs[nl*40 + ck] = v;
    }
    __syncthreads();
    s16x8 af[2];
    #pragma unroll
    for (int mf=0;mf<2;mf++)
      af[mf] = *(const s16x8*)&As[(w*32 + mf*16 + l16)*40 + kg*8];
    #pragma unroll
    for (int nf=0;nf<8;nf++){
      s16x8 bfr = *(const s16x8*)&Bs[(nf*16 + l16)*40 + kg*8];
      #pragma unroll
      for (int mf=0;mf<2;mf++)
        acc[mf][nf] = mfma16(af[mf], bfr, acc[mf][nf]);
    }
  }
  #pragma unroll
  for (int mf=0;mf<2;mf++){
    #pragma unroll
    for (int j=0;j<4;j++){
      const int row = m0 + w*32 + mf*16 + kg*4 + j;
      float* cp = C + (size_t)row*ldc + n0 + l16;
      #pragma unroll
      for (int nf=0;nf<8;nf++){
        const float v = acc[mf][nf][j];
        if (addmode) cp[nf*16] += v; else cp[nf*16] = v;
      }
    }
  }
}

// ---------------- up-proj GEMM with fused GLU epilogue ----------------
// Bw packed [16][1408][32] (GLU column interleave folded into pack).
__global__ __launch_bounds__(256) void k_gemm_up(
    const u16* __restrict__ A,
    const u16* __restrict__ Bw,
    u16* __restrict__ act)
{
  __shared__ u16 As[128*40];
  __shared__ u16 Bs[128*40];
  const int tid = threadIdx.x;
  const int m0 = blockIdx.x * 128;
  const int n0 = blockIdx.y * 128;
  const int w = tid >> 6, l = tid & 63;
  const int l16 = l & 15, kg = l >> 4;
  f32x4 acc[2][8];
  #pragma unroll
  for (int i=0;i<2;i++)
    #pragma unroll
    for (int j=0;j<8;j++) acc[i][j] = (f32x4)0.f;
  for (int kt=0; kt<16; ++kt){
    const int k0 = kt<<5;
    __syncthreads();
    #pragma unroll
    for (int p=0;p<2;p++){
      const int idx = p*256 + tid;
      const int row = idx>>2, kc = (idx&3)*8;
      s16x8 v = *(const s16x8*)(A + (size_t)(m0+row)*D_ + k0 + kc);
      *(s16x8*)&As[row*40 + kc] = v;
    }
    #pragma unroll
    for (int p=0;p<2;p++){
      const int idx = p*256 + tid;
      const int nl = idx>>2, ck = (idx&3)*8;
      s16x8 v = *(const s16x8*)(Bw + (size_t)kt*(2*UP_)*32 + (size_t)(n0+nl)*32 + ck);
      *(s16x8*)&Bs[nl*40 + ck] = v;
    }
    __syncthreads();
    s16x8 af[2];
    #pragma unroll
    for (int mf=0;mf<2;mf++)
      af[mf] = *(const s16x8*)&As[(w*32 + mf*16 + l16)*40 + kg*8];
    #pragma unroll
    for (int nf=0;nf<8;nf++){
      s16x8 bfr = *(const s16x8*)&Bs[(nf*16 + l16)*40 + kg*8];
      #pragma unroll
      for (int mf=0;mf<2;mf++)
        acc[mf][nf] = mfma16(af[mf], bfr, acc[mf][nf]);
    }
  }
  const int n0h = blockIdx.y * 64;   // act column base for this tile
  #pragma unroll
  for (int mf=0;mf<2;mf++){
    #pragma unroll
    for (int j=0;j<4;j++){
      const int row = m0 + w*32 + mf*16 + kg*4 + j;
      u16* ap = act + (size_t)row*UP_ + n0h + l16;
      #pragma unroll
      for (int nf=0;nf<4;nf++){
        const float gg = acc[mf][nf][j];
        const float uu = acc[mf][nf+4][j];
        const float tt = tanh_fast(0.7978845608028654f*(gg + 0.044715f*gg*gg*gg));
        ap[nf*16] = f2bf(0.5f*gg*(1.f+tt)*uu);
      }
    }
  }
}

// ---------------- gate projections (s-chunked), output f16 ----------------
// wg packed per-matrix [4][128][32].
__global__ __launch_bounds__(256) void k_gemm_gates(
    const u16* __restrict__ xcc, const u16* __restrict__ xnbf,
    const u16* __restrict__ wg,
    const float* __restrict__ bgates,
    u16* __restrict__ pre, int s0, int Sc)
{
  __shared__ u16 As[128*40];
  __shared__ u16 Bs[128*40];
  const int tid = threadIdx.x;
  const int m0 = blockIdx.x * 128;
  const int gh = blockIdx.y; const int g = gh>>2, hh = gh&3;
  const u16* Bw = wg + (size_t)gh*DH_*DH_;
  const int w = tid >> 6, l = tid & 63;
  const int l16 = l & 15, kg = l >> 4;
  f32x4 acc[2][8];
  #pragma unroll
  for (int i=0;i<2;i++)
    #pragma unroll
    for (int j=0;j<8;j++) acc[i][j] = (f32x4)0.f;
  for (int kt=0; kt<4; ++kt){
    const int k0 = kt<<5;
    __syncthreads();
    #pragma unroll
    for (int p=0;p<2;p++){
      const int idx = p*256 + tid;
      const int row = idx>>2, kc = (idx&3)*8;
      const int m = m0 + row;
      size_t aoff;
      const u16* Abase;
      if (g < 2){ Abase = xcc;  aoff = (size_t)m*D_; }
      else {
        const int b2 = m / Sc, sl2 = m - b2*Sc;
        Abase = xnbf; aoff = (size_t)(b2*S_ + s0 + sl2)*D_;
      }
      s16x8 v = *(const s16x8*)(Abase + aoff + hh*DH_ + k0 + kc);
      *(s16x8*)&As[row*40 + kc] = v;
    }
    #pragma unroll
    for (int p=0;p<2;p++){
      const int idx = p*256 + tid;
      const int nl = idx>>2, ck = (idx&3)*8;
      s16x8 v = *(const s16x8*)(Bw + (size_t)kt*DH_*32 + (size_t)nl*32 + ck);
      *(s16x8*)&Bs[nl*40 + ck] = v;
    }
    __syncthreads();
    s16x8 af[2];
    #pragma unroll
    for (int mf=0;mf<2;mf++)
      af[mf] = *(const s16x8*)&As[(w*32 + mf*16 + l16)*40 + kg*8];
    #pragma unroll
    for (int nf=0;nf<8;nf++){
      s16x8 bfr = *(const s16x8*)&Bs[(nf*16 + l16)*40 + kg*8];
      #pragma unroll
      for (int mf=0;mf<2;mf++)
        acc[mf][nf] = mfma16(af[mf], bfr, acc[mf][nf]);
    }
  }
  #pragma unroll
  for (int mf=0;mf<2;mf++){
    #pragma unroll
    for (int j=0;j<4;j++){
      const int m = m0 + w*32 + mf*16 + kg*4 + j;
      const int b2 = m / Sc;
      const int sl2 = m - b2*Sc;
      #pragma unroll
      for (int nf=0;nf<8;nf++){
        const int col = nf*16 + l16;
        const float bias = bgates[g*D_ + hh*128 + col];
        pre[(((size_t)g*Sc + sl2)*B_ + b2)*D_ + hh*128 + col] =
            __builtin_bit_cast(u16, (f16)(acc[mf][nf][j] + bias));
      }
    }
  }
}

// ---------------- recurrent scan (1 batch/block, 512 blocks, 2 blocks/CU) ----------------
// grid (B, NH) = 512 blocks, 512 threads = 8 waves, __launch_bounds__(512,4) so
// TWO blocks co-reside per CU -- one block's barrier stalls hide under the
// other's execution. Wave w: gate g=w>>1, col-half ch=w&1. Only A-tile row 0
// carries the batch. Phase B: waves 0-1 at full 64-lane width (1 col/thread).
// lgkm-only barriers; pre prefetched 2 steps ahead as raw u16; DPP GroupNorm.
__global__ __launch_bounds__(512, 4) void k_scan(
    const u16* __restrict__ pre,      // f16 [4][Sc][B][D]
    const float* __restrict__ rg,
    const float* __restrict__ gnw,
    u16* __restrict__ ybuf,           // bf16 [B][S][D]
    float* __restrict__ st, int s0, int Sc)
{
  const int t   = threadIdx.x;
  const int hh  = blockIdx.y;
  const int bb  = blockIdx.x;       // single batch
  const int w   = t >> 6;
  const int l   = t & 63;
  const int g   = w >> 1;
  const int ch  = w & 1;
  const int la  = l >> 4, lb = l & 15;

  __shared__ __align__(16) char  hA[16*256];   // f16 [16][128], row 0 live
  __shared__ __align__(16) float recl[4*132];  // [gate][132]
  __shared__ float red[2][2];                  // [wh][{sum,sq}]

  // ---- R fragments (f16) in registers ----
  f16x8 Rf[4][4];
  {
    const float* rbase = rg + ((size_t)(g*NH_ + hh)*DH_)*DH_ + ch*64;
    #pragma unroll
    for (int ct=0; ct<4; ++ct)
      #pragma unroll
      for (int ks=0; ks<4; ++ks){
        f16x8 f;
        #pragma unroll
        for (int j=0;j<8;j++)
          f[j] = (f16)rbase[(size_t)(ks*32 + la*8 + j)*DH_ + ct*16 + lb];
        Rf[ct][ks] = f;
      }
  }

  // ---- pointwise mapping & state (threads 0-127 = waves 0-1) ----
  const bool act = (t < 128);
  const int col = t & 127;
  const int wh  = t >> 6;           // 0/1 for act threads
  const int SCMP = B_*NH_*DH_;
  const int is  = (bb*NH_ + hh)*128 + col;

  for (int i = t; i < 16*128; i += 512) ((u16*)hA)[i] = 0;   // clear all rows
  float hst=0.f, cst=0.f, nst=0.f, mst=0.f;
  if (act){
    hst = st[0*SCMP + is];
    cst = st[1*SCMP + is];
    nst = st[2*SCMP + is];
    mst = st[3*SCMP + is];
    const int slot = col >> 3;
    *(u16*)&hA[((slot&15)<<4) + (col&7)*2] = __builtin_bit_cast(u16, (f16)hst);
  }
  const float gws = gnw[hh*128 + col];
  const u16* prebase = pre + (size_t)bb*D_ + hh*128 + col;
  const size_t gstride = (size_t)Sc*B_*D_;
  const size_t sstride = (size_t)B_*D_;
  u16 pc16[4]={0,0,0,0}, pn16[4]={0,0,0,0};
  if (act){
    #pragma unroll
    for (int g2=0; g2<4; ++g2)
      pc16[g2] = prebase[g2*gstride];
    const int s1c = (Sc > 1) ? 1 : 0;
    #pragma unroll
    for (int g2=0; g2<4; ++g2)
      pn16[g2] = prebase[g2*gstride + (size_t)s1c*sstride];
  }
  __syncthreads();

  for (int sl=0; sl<Sc; ++sl){
    // ---- prefetch step sl+2 as raw u16 (no cvt -> no vmcnt drain here) ----
    u16 pl16[4]={0,0,0,0};
    if (act){
      const int sn = (sl+2 < Sc) ? sl+2 : Sc-1;
      #pragma unroll
      for (int g2=0; g2<4; ++g2)
        pl16[g2] = prebase[g2*gstride + (size_t)sn*sstride];
    }

    // ---- Phase A: rec = h @ R via MFMA (two independent 2-deep chains) ----
    f32x4 accA[4], accB[4];
    #pragma unroll
    for (int ct=0; ct<4; ++ct){ accA[ct] = (f32x4)0.f; accB[ct] = (f32x4)0.f; }
    #pragma unroll
    for (int ks=0; ks<4; ++ks){
      const int slot = ks*4 + la;
      f16x8 af = *(const f16x8*)&hA[lb*256 + (((slot ^ lb)&15)<<4)];
      if (ks < 2){
        #pragma unroll
        for (int ct=0; ct<4; ++ct) accA[ct] = mfma16h(af, Rf[ct][ks], accA[ct]);
      } else {
        #pragma unroll
        for (int ct=0; ct<4; ++ct) accB[ct] = mfma16h(af, Rf[ct][ks], accB[ct]);
      }
    }
    if (la == 0){
      #pragma unroll
      for (int ct=0; ct<4; ++ct)
        recl[g*132 + ch*64 + ct*16 + lb] = accA[ct][0] + accB[ct][0];
    }
    bar_lgkm();

    // ---- Phase B: pointwise, waves 0-1, 1 col/thread ----
    float hv = 0.f;
    if (act){
      const float iraw = (float)__builtin_bit_cast(f16, pc16[0]) + recl[0*132 + col];
      const float fraw = (float)__builtin_bit_cast(f16, pc16[1]) + recl[1*132 + col];
      const float zraw = (float)__builtin_bit_cast(f16, pc16[2]) + recl[2*132 + col];
      const float oraw = (float)__builtin_bit_cast(f16, pc16[3]) + recl[3*132 + col];
      const float lf   = mst + logsig_fast(fraw);
      const float mn   = fmaxf(iraw, lf);
      const float ig   = __expf(iraw - mn);
      const float fg   = __expf(lf - mn);
      cst = fg*cst + ig*tanh_fast(zraw);
      nst = fg*nst + ig;
      mst = mn;
      hv = sigmoid_fast(oraw) * cst * frcp(nst);
      hst = hv;
      const int slot = col >> 3;
      *(u16*)&hA[((slot&15)<<4) + (col&7)*2] = __builtin_bit_cast(u16, (f16)hv);
      const float s1 = wave_sum64(hv);
      const float s2 = wave_sum64(hv*hv);
      if (l == 0){ red[wh][0] = s1; red[wh][1] = s2; }
    }
    bar_lgkm();

    // ---- tail: GroupNorm + y store (overlaps next step's Phase A) ----
    if (act){
      const float sum = red[0][0] + red[1][0];
      const float sq  = red[0][1] + red[1][1];
      const float mu  = sum * (1.f/128.f);
      const float var = sq * (1.f/128.f) - mu*mu;
      const float y   = (hv - mu) * rsqrtf(var + 1e-5f) * gws;
      ybuf[((size_t)bb*S_ + (s0+sl))*D_ + hh*128 + col] = f2bf(y);
      pc16[0]=pn16[0]; pc16[1]=pn16[1]; pc16[2]=pn16[2]; pc16[3]=pn16[3];
      pn16[0]=pl16[0]; pn16[1]=pl16[1]; pn16[2]=pl16[2]; pn16[3]=pl16[3];
    }
  }
  if (act){
    st[0*SCMP + is] = hst;
    st[1*SCMP + is] = cst;
    st[2*SCMP + is] = nst;
    st[3*SCMP + is] = mst;
  }
}

// ---------------- final: post-LN(last token) -> fc1+relu -> fc2 ----------------
__global__ __launch_bounds__(256) void k_head(const float* __restrict__ h,
     const float* __restrict__ pw, const float* __restrict__ f1w, const float* __restrict__ f1b,
     const float* __restrict__ f2w, const float* __restrict__ f2bias, float* __restrict__ out)
{
  const int b = blockIdx.x, tid = threadIdx.x;
  __shared__ float nrm[512];
  __shared__ float a1[256];
  __shared__ float red[4][2];
  const float* row = h + ((size_t)b*S_ + (S_-1))*D_;
  const float v0 = row[tid], v1 = row[tid+256];
  float s = v0+v1, q = v0*v0+v1*v1;
  #pragma unroll
  for (int off=32; off; off>>=1){ s += __shfl_down(s,off,64); q += __shfl_down(q,off,64); }
  if ((tid&63)==0){ red[tid>>6][0]=s; red[tid>>6][1]=q; }
  __syncthreads();
  const float sum = red[0][0]+red[1][0]+red[2][0]+red[3][0];
  const float sq  = red[0][1]+red[1][1]+red[2][1]+red[3][1];
  const float mu  = sum*(1.f/D_), var = sq*(1.f/D_) - mu*mu;
  const float inv = rsqrtf(var+1e-5f);
  nrm[tid]      = (v0-mu)*inv*pw[tid];
  nrm[tid+256]  = (v1-mu)*inv*pw[tid+256];
  __syncthreads();
  float acc = f1b[tid];
  for (int d=0; d<D_; ++d) acc += nrm[d]*f1w[(size_t)d*256 + tid];
  a1[tid] = fmaxf(acc, 0.f);
  __syncthreads();
  if (tid < FD_){
    float o = f2bias[tid];
    for (int i=0;i<256;++i) o += a1[i]*f2w[(size_t)i*FD_ + tid];
    out[b*FD_ + tid] = o;
  }
}

// ---------------- launcher ----------------
extern "C" void kernel_launch(void* const* d_in, const int* in_sizes, int n_in,
                              void* d_out, int out_size, void* d_ws, size_t ws_size,
                              hipStream_t stream)
{
  const float* x       = (const float*)d_in[0];
  const float* w_in    = (const float*)d_in[1];
  const float* b_in    = (const float*)d_in[2];
  const float* ln1_w   = (const float*)d_in[3];
  const float* conv_w  = (const float*)d_in[4];
  const float* conv_b  = (const float*)d_in[5];
  const float* w_gates = (const float*)d_in[6];
  const float* r_gates = (const float*)d_in[7];
  const float* b_gates = (const float*)d_in[8];
  const float* gn_w    = (const float*)d_in[9];
  const float* ln2_w   = (const float*)d_in[10];
  const float* ff_up   = (const float*)d_in[11];
  const float* ff_down = (const float*)d_in[12];
  const float* post_ln = (const float*)d_in[13];
  const float* fc1_w   = (const float*)d_in[14];
  const float* fc1_b   = (const float*)d_in[15];
  const float* fc2_w   = (const float*)d_in[16];
  const float* fc2_b   = (const float*)d_in[17];
  float* out = (float*)d_out;

  // ---- persistent workspace layout (bytes) ----
  char* ws = (char*)d_ws;
  const size_t OFF_H     = 0;           // f32 h           52,428,800
  const size_t OFF_XNBF  = 52428800;    // bf16 xn/xn2     26,214,400
  const size_t OFF_WGBF  = 78643200;    // bf16 w_gates     1,048,576
  const size_t OFF_UPBF  = 79691776;    // bf16 ff_up       2,883,584
  const size_t OFF_DNBF  = 82575360;    // bf16 ff_down     1,441,792
  const size_t OFF_STATE = 84017152;    // f32 scan state   1,048,576
  const size_t OFF_YBUF  = 85065728;    // bf16 y          26,214,400
  const size_t OFF_CHUNK = 111280128;   // chunked region (rest)

  // per-s chunk cost: pre f16 (524,288) + xc bf16 (131,072)
  if (ws_size < OFF_CHUNK + 655360ull){
    k_sentinel<<<4, 256, 0, stream>>>(out, out_size);
    return;
  }
  const size_t CR = ws_size - OFF_CHUNK;
  int Sc = (int)(CR / 655360ull); if (Sc > S_) Sc = S_;
  // per-M-row cost for FFN phase: act bf16 (UP*2 = 1408)
  int Mc = (int)((CR / 1408ull) & ~(size_t)127); if (Mc > M_) Mc = M_;

  float* h     = (float*)(ws + OFF_H);
  u16*   xnbf  = (u16*)  (ws + OFF_XNBF);
  u16*   wgbf  = (u16*)  (ws + OFF_WGBF);
  u16*   upbf  = (u16*)  (ws + OFF_UPBF);
  u16*   dnbf  = (u16*)  (ws + OFF_DNBF);
  float* st    = (float*)(ws + OFF_STATE);
  u16*   ybuf  = (u16*)  (ws + OFF_YBUF);
  u16*   xcc   = (u16*)  (ws + OFF_CHUNK);
  u16*   prec  = (u16*)  (ws + OFF_CHUNK + (size_t)Sc*131072);
  u16*   actc  = (u16*)  (ws + OFF_CHUNK);    // aliases xcc/prec (disjoint in time)

  // cast + pack weights to bf16 fragment order (one-time)
  {
    int n1 = NB_*4*NH_*DH_*DH_;  k_cast_pack_gates<<<(n1+255)/256, 256, 0, stream>>>(w_gates, wgbf, n1);
    int n2 = NB_*D_*2*UP_;       k_cast_pack_up<<<(n2+255)/256, 256, 0, stream>>>(ff_up, upbf, n2);
    int n3 = NB_*UP_*D_;         k_cast_pack_dn<<<(n3+255)/256, 256, 0, stream>>>(ff_down, dnbf, n3);
  }

  k_inproj<<<M_/8, 256, 0, stream>>>(x, w_in, b_in, h);

  for (int blk=0; blk<NB_; ++blk){
    k_ln<<<M_, 128, 0, stream>>>(h, ln1_w + blk*D_, xnbf);
    k_zero<<<1024, 256, 0, stream>>>(st, 4*B_*NH_*DH_);
    for (int s0=0; s0<S_; s0+=Sc){
      const int scur = (S_ - s0 < Sc) ? (S_ - s0) : Sc;
      k_conv<<<scur*64, 256, 0, stream>>>(xnbf, conv_w + blk*KK_*D_, conv_b + blk*D_,
                                          xcc, s0, scur);
      dim3 gg((B_*scur)/128, 16);
      k_gemm_gates<<<gg, 256, 0, stream>>>(xcc, xnbf,
          wgbf + (size_t)blk*4*NH_*DH_*DH_, b_gates + (size_t)blk*4*D_, prec, s0, scur);
      dim3 gs(B_, NH_);
      k_scan<<<gs, 512, 0, stream>>>(prec, r_gates + (size_t)blk*4*NH_*DH_*DH_,
                                     gn_w + blk*D_, ybuf, st, s0, scur);
    }
    // h += y ; LN2 -> bf16
    k_addln<<<M_, 128, 0, stream>>>(h, ybuf, ln2_w + blk*D_, xnbf);
    // M-chunked FFN: up+GLU fused -> act(bf16); down += into h
    for (int m0c=0; m0c<M_; m0c+=Mc){
      const int mcur = (M_ - m0c < Mc) ? (M_ - m0c) : Mc;
      dim3 g1(mcur/128, (2*UP_)/128);   // 11 n-blocks
      k_gemm_up<<<g1, 256, 0, stream>>>(xnbf + (size_t)m0c*D_,
                                        upbf + (size_t)blk*D_*2*UP_, actc);
      dim3 g2(mcur/128, D_/128);        // 4 n-blocks
      k_gemm_ffn<<<g2, 256, 0, stream>>>(actc, UP_,
                                         dnbf + (size_t)blk*UP_*D_, D_,
                                         h + (size_t)m0c*D_, D_, UP_, 1);
    }
  }

  k_head<<<B_, 256, 0, stream>>>(h, post_ln, fc1_w, fc1_b, fc2_w, fc2_b, out);
}

// Round 14
// 974.834 us; speedup vs baseline: 1.2244x; 1.2244x over previous
//
#include <hip/hip_runtime.h>

// ---------------- problem constants ----------------
#define B_  128
#define S_  200
#define F_  32
#define D_  512
#define NH_ 4
#define DH_ 128
#define KK_ 4
#define NB_ 2
#define UP_ 704
#define FD_ 7
#define M_  (B_*S_)   // 25600 rows

typedef unsigned short u16;
typedef _Float16 f16;
typedef __attribute__((ext_vector_type(8))) _Float16 f16x8;
typedef __attribute__((ext_vector_type(8))) short  s16x8;
typedef __attribute__((ext_vector_type(4))) float  f32x4;

__device__ __forceinline__ u16 f2bf(float f){
  unsigned x = __builtin_bit_cast(unsigned, f);
  return (u16)((x + 0x7fffu + ((x>>16)&1u)) >> 16);   // RNE
}
__device__ __forceinline__ float bf2f(u16 u){
  return __builtin_bit_cast(float, (unsigned)u << 16);
}
__device__ __forceinline__ f32x4 mfma16(s16x8 a, s16x8 b, f32x4 c){
  return __builtin_amdgcn_mfma_f32_16x16x32_bf16(a, b, c, 0, 0, 0);
}
__device__ __forceinline__ f32x4 mfma16h(f16x8 a, f16x8 b, f32x4 c){
  return __builtin_amdgcn_mfma_f32_16x16x32_f16(a, b, c, 0, 0, 0);
}
// fast native math (v_exp_f32 / v_log_f32 / v_rcp_f32), rel err ~1e-6
__device__ __forceinline__ float frcp(float x){ return __builtin_amdgcn_rcpf(x); }
__device__ __forceinline__ float tanh_fast(float z){
  const float u = __expf(-2.f*fabsf(z));          // in (0,1]
  const float t = (1.f-u)*frcp(1.f+u);
  return copysignf(t, z);
}
__device__ __forceinline__ float logsig_fast(float f){  // log(sigmoid(f))
  const float t = __expf(-fabsf(f));
  return fminf(f, 0.f) - __logf(1.f + t);
}
__device__ __forceinline__ float sigmoid_fast(float x){
  return frcp(1.f + __expf(-x));
}
// lgkm-only barrier: does NOT drain vmcnt, so global prefetch loads/stores
// stay in flight across it. All cross-wave data moves via LDS.
__device__ __forceinline__ void bar_lgkm(){
  __builtin_amdgcn_sched_barrier(0);
  asm volatile("s_waitcnt lgkmcnt(0)" ::: "memory");
  __builtin_amdgcn_s_barrier();
  __builtin_amdgcn_sched_barrier(0);
}
// 64-lane sum via DPP (VALU pipe, no LDS). ctrl must be immediate -> template.
template<int CTRL>
__device__ __forceinline__ float dpp_add(float v){
  int x = __builtin_amdgcn_update_dpp(0, __builtin_bit_cast(int, v), CTRL, 0xf, 0xf, false);
  return v + __builtin_bit_cast(float, x);
}
__device__ __forceinline__ float wave_sum64(float v){
  v = dpp_add<0x111>(v);   // row_shr:1
  v = dpp_add<0x112>(v);   // row_shr:2
  v = dpp_add<0x114>(v);   // row_shr:4
  v = dpp_add<0x118>(v);   // row_shr:8
  v = dpp_add<0x142>(v);   // row_bcast:15
  v = dpp_add<0x143>(v);   // row_bcast:31
  return __builtin_bit_cast(float, __builtin_amdgcn_readlane(__builtin_bit_cast(int, v), 63));
}

// ---------------- tiny utility kernels ----------------
__global__ void k_zero(float* __restrict__ p, int n){
  int i = blockIdx.x*256 + threadIdx.x;
  if (i < n) p[i] = 0.f;
}
__global__ void k_sentinel(float* __restrict__ out, int n){
  int i = blockIdx.x*256 + threadIdx.x;
  if (i < n) out[i] = -12345.0f;
}

// ---- weight cast+pack kernels: output k-slab fragment order [K/32][N][32] ----
// gates: NB*4*NH matrices of [128][128] -> per-mat [4][128][32]
__global__ void k_cast_pack_gates(const float* __restrict__ in, u16* __restrict__ out, int n){
  int i = blockIdx.x*256 + threadIdx.x;
  if (i >= n) return;
  const int mat = i >> 14;            // /16384
  const int rem = i & 16383;
  const int slab = rem >> 12;         // /(128*32)
  const int r2   = rem & 4095;
  const int nn   = r2 >> 5;
  const int kk   = r2 & 31;
  out[i] = f2bf(in[(size_t)mat*16384 + (size_t)(slab*32 + kk)*DH_ + nn]);
}
// ff_up: [NB][D=512][2UP=1408] -> [NB][16][1408][32], with GLU column interleave:
// packed col n -> src col: j=n&127, t=n>>7; col = j<64 ? t*64+j : UP + t*64 + (j-64)
__global__ void k_cast_pack_up(const float* __restrict__ in, u16* __restrict__ out, int n){
  int i = blockIdx.x*256 + threadIdx.x;
  if (i >= n) return;
  const int per = 512*1408;
  const int blk = i / per;
  const int rem = i - blk*per;
  const int slab = rem / (1408*32);
  const int r2   = rem - slab*(1408*32);
  const int nn   = r2 >> 5;
  const int kk   = r2 & 31;
  const int j = nn & 127, tt = nn >> 7;
  const int col = (j < 64) ? (tt*64 + j) : (UP_ + tt*64 + (j - 64));
  out[i] = f2bf(in[(size_t)(blk*512 + slab*32 + kk)*(2*UP_) + col]);
}
// ff_down: [NB][UP=704][D=512] -> [NB][22][512][32]
__global__ void k_cast_pack_dn(const float* __restrict__ in, u16* __restrict__ out, int n){
  int i = blockIdx.x*256 + threadIdx.x;
  if (i >= n) return;
  const int per = 704*512;
  const int blk = i / per;
  const int rem = i - blk*per;
  const int slab = rem / (512*32);
  const int r2   = rem - slab*(512*32);
  const int nn   = r2 >> 5;
  const int kk   = r2 & 31;
  out[i] = f2bf(in[(size_t)(blk*704 + slab*32 + kk)*D_ + nn]);
}

// ---------------- input projection: h = x @ w_in + b_in ----------------
__global__ __launch_bounds__(256) void k_inproj(const float* __restrict__ x,
    const float* __restrict__ w, const float* __restrict__ bias, float* __restrict__ h)
{
  __shared__ float xs[8][32];
  const int m0 = blockIdx.x*8, tid = threadIdx.x;
  xs[tid>>5][tid&31] = x[(size_t)(m0 + (tid>>5))*F_ + (tid&31)];
  __syncthreads();
  #pragma unroll
  for (int hf=0; hf<2; ++hf){
    const int e = tid + hf*256;
    float a[8];
    const float bb = bias[e];
    #pragma unroll
    for (int r=0;r<8;r++) a[r]=bb;
    for (int f=0; f<F_; ++f){
      const float wv = w[(size_t)f*D_ + e];
      #pragma unroll
      for (int r=0;r<8;r++) a[r] += xs[r][f]*wv;
    }
    #pragma unroll
    for (int r=0;r<8;r++) h[(size_t)(m0+r)*D_ + e] = a[r];
  }
}

// ---------------- LayerNorm over D=512 -> bf16 ----------------
__global__ __launch_bounds__(128) void k_ln(const float* __restrict__ in, const float* __restrict__ w,
      u16* __restrict__ outb)
{
  const int row = blockIdx.x, tid = threadIdx.x;
  const f32x4* rp = (const f32x4*)(in + (size_t)row*D_);
  f32x4 v = rp[tid];
  float s = v[0]+v[1]+v[2]+v[3];
  float q = v[0]*v[0]+v[1]*v[1]+v[2]*v[2]+v[3]*v[3];
  #pragma unroll
  for (int off=32; off; off>>=1){ s += __shfl_down(s,off,64); q += __shfl_down(q,off,64); }
  __shared__ float red[2][2];
  if ((tid&63)==0){ red[tid>>6][0]=s; red[tid>>6][1]=q; }
  __syncthreads();
  const float sum = red[0][0]+red[1][0], sq = red[0][1]+red[1][1];
  const float mu  = sum*(1.f/D_);
  const float var = sq*(1.f/D_) - mu*mu;
  const float inv = rsqrtf(var + 1e-5f);
  f32x4 wv = ((const f32x4*)w)[tid];
  ushort4 ob;
  ob.x=f2bf((v[0]-mu)*inv*wv[0]); ob.y=f2bf((v[1]-mu)*inv*wv[1]);
  ob.z=f2bf((v[2]-mu)*inv*wv[2]); ob.w=f2bf((v[3]-mu)*inv*wv[3]);
  ((ushort4*)(outb + (size_t)row*D_))[tid] = ob;
}

// ---------------- fused residual add + LayerNorm: h += y(bf16); out = LN(h) ----------------
__global__ __launch_bounds__(128) void k_addln(float* __restrict__ h, const u16* __restrict__ y,
      const float* __restrict__ w, u16* __restrict__ outb)
{
  const int row = blockIdx.x, tid = threadIdx.x;
  f32x4 v = ((const f32x4*)(h + (size_t)row*D_))[tid];
  ushort4 yq = ((const ushort4*)(y + (size_t)row*D_))[tid];
  v[0]+=bf2f(yq.x); v[1]+=bf2f(yq.y); v[2]+=bf2f(yq.z); v[3]+=bf2f(yq.w);
  ((f32x4*)(h + (size_t)row*D_))[tid] = v;
  float s = v[0]+v[1]+v[2]+v[3];
  float q = v[0]*v[0]+v[1]*v[1]+v[2]*v[2]+v[3]*v[3];
  #pragma unroll
  for (int off=32; off; off>>=1){ s += __shfl_down(s,off,64); q += __shfl_down(q,off,64); }
  __shared__ float red[2][2];
  if ((tid&63)==0){ red[tid>>6][0]=s; red[tid>>6][1]=q; }
  __syncthreads();
  const float sum = red[0][0]+red[1][0], sq = red[0][1]+red[1][1];
  const float mu  = sum*(1.f/D_);
  const float var = sq*(1.f/D_) - mu*mu;
  const float inv = rsqrtf(var + 1e-5f);
  f32x4 wv = ((const f32x4*)w)[tid];
  ushort4 ob;
  ob.x=f2bf((v[0]-mu)*inv*wv[0]); ob.y=f2bf((v[1]-mu)*inv*wv[1]);
  ob.z=f2bf((v[2]-mu)*inv*wv[2]); ob.w=f2bf((v[3]-mu)*inv*wv[3]);
  ((ushort4*)(outb + (size_t)row*D_))[tid] = ob;
}

// ---------------- causal depthwise conv (K=4) + SiLU -> bf16, s-chunked ----------------
__global__ void k_conv(const u16* __restrict__ xnbf, const float* __restrict__ cw,
                       const float* __restrict__ cb, u16* __restrict__ xcc,
                       int s0, int Sc)
{
  const int idx = blockIdx.x*256 + threadIdx.x;   // over B*Sc*128 quads
  const int e4 = idx & 127;
  const int sl = (idx >> 7) % Sc;
  const int b  = idx / (128*Sc);
  const int s  = s0 + sl;
  f32x4 acc = ((const f32x4*)cb)[e4];
  #pragma unroll
  for (int k=0;k<KK_;k++){
    const int sp = s - (KK_-1) + k;
    if (sp >= 0){
      f32x4 w4 = ((const f32x4*)cw)[k*128 + e4];
      ushort4 xq = ((const ushort4*)xnbf)[(size_t)(b*S_ + sp)*128 + e4];
      acc[0] += w4[0]*bf2f(xq.x);
      acc[1] += w4[1]*bf2f(xq.y);
      acc[2] += w4[2]*bf2f(xq.z);
      acc[3] += w4[3]*bf2f(xq.w);
    }
  }
  ushort4 o;
  float a;
  a=acc[0]; o.x=f2bf(a*sigmoid_fast(a));
  a=acc[1]; o.y=f2bf(a*sigmoid_fast(a));
  a=acc[2]; o.z=f2bf(a*sigmoid_fast(a));
  a=acc[3]; o.w=f2bf(a*sigmoid_fast(a));
  ((ushort4*)xcc)[idx] = o;
}

// ---------------- bf16 MFMA GEMM (down-proj): C[M,N] += A[M,K] @ Bpacked ----------------
// Bw packed [K/32][N][32]; ldb = N.
__global__ __launch_bounds__(256) void k_gemm_ffn(
    const u16* __restrict__ A, int lda,
    const u16* __restrict__ Bw, int ldb,
    float* __restrict__ C, int ldc,
    int Kdim, int addmode)
{
  __shared__ u16 As[128*40];
  __shared__ u16 Bs[128*40];
  const int tid = threadIdx.x;
  const int m0 = blockIdx.x * 128;
  const int n0 = blockIdx.y * 128;
  const int w = tid >> 6, l = tid & 63;
  const int l16 = l & 15, kg = l >> 4;
  f32x4 acc[2][8];
  #pragma unroll
  for (int i=0;i<2;i++)
    #pragma unroll
    for (int j=0;j<8;j++) acc[i][j] = (f32x4)0.f;
  const int nk = Kdim >> 5;
  for (int kt=0; kt<nk; ++kt){
    const int k0 = kt<<5;
    __syncthreads();
    #pragma unroll
    for (int p=0;p<2;p++){
      const int idx = p*256 + tid;
      const int row = idx>>2, kc = (idx&3)*8;
      s16x8 v = *(const s16x8*)(A + (size_t)(m0+row)*lda + k0 + kc);
      *(s16x8*)&As[row*40 + kc] = v;
    }
    #pragma unroll
    for (int p=0;p<2;p++){
      const int idx = p*256 + tid;
      const int nl = idx>>2, ck = (idx&3)*8;
      s16x8 v = *(const s16x8*)(Bw + (size_t)kt*ldb*32 + (size_t)(n0+nl)*32 + ck);
      *(s16x8*)&Bs[nl*40 + ck] = v;
    }
    __syncthreads();
    s16x8 af[2];
    #pragma unroll
    for (int mf=0;mf<2;mf++)
      af[mf] = *(const s16x8*)&As[(w*32 + mf*16 + l16)*40 + kg*8];
    #pragma unroll
    for (int nf=0;nf<8;nf++){
      s16x8 bfr = *(const s16x8*)&Bs[(nf*16 + l16)*40 + kg*8];
      #pragma unroll
      for (int mf=0;mf<2;mf++)
        acc[mf][nf] = mfma16(af[mf], bfr, acc[mf][nf]);
    }
  }
  #pragma unroll
  for (int mf=0;mf<2;mf++){
    #pragma unroll
    for (int j=0;j<4;j++){
      const int row = m0 + w*32 + mf*16 + kg*4 + j;
      float* cp = C + (size_t)row*ldc + n0 + l16;
      #pragma unroll
      for (int nf=0;nf<8;nf++){
        const float v = acc[mf][nf][j];
        if (addmode) cp[nf*16] += v; else cp[nf*16] = v;
      }
    }
  }
}

// ---------------- up-proj GEMM with fused GLU epilogue ----------------
// Bw packed [16][1408][32] (GLU column interleave folded into pack).
__global__ __launch_bounds__(256) void k_gemm_up(
    const u16* __restrict__ A,
    const u16* __restrict__ Bw,
    u16* __restrict__ act)
{
  __shared__ u16 As[128*40];
  __shared__ u16 Bs[128*40];
  const int tid = threadIdx.x;
  const int m0 = blockIdx.x * 128;
  const int n0 = blockIdx.y * 128;
  const int w = tid >> 6, l = tid & 63;
  const int l16 = l & 15, kg = l >> 4;
  f32x4 acc[2][8];
  #pragma unroll
  for (int i=0;i<2;i++)
    #pragma unroll
    for (int j=0;j<8;j++) acc[i][j] = (f32x4)0.f;
  for (int kt=0; kt<16; ++kt){
    const int k0 = kt<<5;
    __syncthreads();
    #pragma unroll
    for (int p=0;p<2;p++){
      const int idx = p*256 + tid;
      const int row = idx>>2, kc = (idx&3)*8;
      s16x8 v = *(const s16x8*)(A + (size_t)(m0+row)*D_ + k0 + kc);
      *(s16x8*)&As[row*40 + kc] = v;
    }
    #pragma unroll
    for (int p=0;p<2;p++){
      const int idx = p*256 + tid;
      const int nl = idx>>2, ck = (idx&3)*8;
      s16x8 v = *(const s16x8*)(Bw + (size_t)kt*(2*UP_)*32 + (size_t)(n0+nl)*32 + ck);
      *(s16x8*)&Bs[nl*40 + ck] = v;
    }
    __syncthreads();
    s16x8 af[2];
    #pragma unroll
    for (int mf=0;mf<2;mf++)
      af[mf] = *(const s16x8*)&As[(w*32 + mf*16 + l16)*40 + kg*8];
    #pragma unroll
    for (int nf=0;nf<8;nf++){
      s16x8 bfr = *(const s16x8*)&Bs[(nf*16 + l16)*40 + kg*8];
      #pragma unroll
      for (int mf=0;mf<2;mf++)
        acc[mf][nf] = mfma16(af[mf], bfr, acc[mf][nf]);
    }
  }
  const int n0h = blockIdx.y * 64;   // act column base for this tile
  #pragma unroll
  for (int mf=0;mf<2;mf++){
    #pragma unroll
    for (int j=0;j<4;j++){
      const int row = m0 + w*32 + mf*16 + kg*4 + j;
      u16* ap = act + (size_t)row*UP_ + n0h + l16;
      #pragma unroll
      for (int nf=0;nf<4;nf++){
        const float gg = acc[mf][nf][j];
        const float uu = acc[mf][nf+4][j];
        const float tt = tanh_fast(0.7978845608028654f*(gg + 0.044715f*gg*gg*gg));
        ap[nf*16] = f2bf(0.5f*gg*(1.f+tt)*uu);
      }
    }
  }
}

// ---------------- gate projections (s-chunked), output f16 ----------------
// wg packed per-matrix [4][128][32].
__global__ __launch_bounds__(256) void k_gemm_gates(
    const u16* __restrict__ xcc, const u16* __restrict__ xnbf,
    const u16* __restrict__ wg,
    const float* __restrict__ bgates,
    u16* __restrict__ pre, int s0, int Sc)
{
  __shared__ u16 As[128*40];
  __shared__ u16 Bs[128*40];
  const int tid = threadIdx.x;
  const int m0 = blockIdx.x * 128;
  const int gh = blockIdx.y; const int g = gh>>2, hh = gh&3;
  const u16* Bw = wg + (size_t)gh*DH_*DH_;
  const int w = tid >> 6, l = tid & 63;
  const int l16 = l & 15, kg = l >> 4;
  f32x4 acc[2][8];
  #pragma unroll
  for (int i=0;i<2;i++)
    #pragma unroll
    for (int j=0;j<8;j++) acc[i][j] = (f32x4)0.f;
  for (int kt=0; kt<4; ++kt){
    const int k0 = kt<<5;
    __syncthreads();
    #pragma unroll
    for (int p=0;p<2;p++){
      const int idx = p*256 + tid;
      const int row = idx>>2, kc = (idx&3)*8;
      const int m = m0 + row;
      size_t aoff;
      const u16* Abase;
      if (g < 2){ Abase = xcc;  aoff = (size_t)m*D_; }
      else {
        const int b2 = m / Sc, sl2 = m - b2*Sc;
        Abase = xnbf; aoff = (size_t)(b2*S_ + s0 + sl2)*D_;
      }
      s16x8 v = *(const s16x8*)(Abase + aoff + hh*DH_ + k0 + kc);
      *(s16x8*)&As[row*40 + kc] = v;
    }
    #pragma unroll
    for (int p=0;p<2;p++){
      const int idx = p*256 + tid;
      const int nl = idx>>2, ck = (idx&3)*8;
      s16x8 v = *(const s16x8*)(Bw + (size_t)kt*DH_*32 + (size_t)nl*32 + ck);
      *(s16x8*)&Bs[nl*40 + ck] = v;
    }
    __syncthreads();
    s16x8 af[2];
    #pragma unroll
    for (int mf=0;mf<2;mf++)
      af[mf] = *(const s16x8*)&As[(w*32 + mf*16 + l16)*40 + kg*8];
    #pragma unroll
    for (int nf=0;nf<8;nf++){
      s16x8 bfr = *(const s16x8*)&Bs[(nf*16 + l16)*40 + kg*8];
      #pragma unroll
      for (int mf=0;mf<2;mf++)
        acc[mf][nf] = mfma16(af[mf], bfr, acc[mf][nf]);
    }
  }
  #pragma unroll
  for (int mf=0;mf<2;mf++){
    #pragma unroll
    for (int j=0;j<4;j++){
      const int m = m0 + w*32 + mf*16 + kg*4 + j;
      const int b2 = m / Sc;
      const int sl2 = m - b2*Sc;
      #pragma unroll
      for (int nf=0;nf<8;nf++){
        const int col = nf*16 + l16;
        const float bias = bgates[g*D_ + hh*128 + col];
        pre[(((size_t)g*Sc + sl2)*B_ + b2)*D_ + hh*128 + col] =
            __builtin_bit_cast(u16, (f16)(acc[mf][nf][j] + bias));
      }
    }
  }
}

// ---------------- recurrent scan (round-12 version: dual-barrier, DPP, raw-u16 prefetch) ----------------
// grid (B/2, NH), 512 threads = 8 waves. Wave w: gate g=w>>1, col-half ch=w&1.
// Phase B: waves 0-3, full 64-lane width (1 col/thread). lgkm-only barriers;
// pre prefetched 2 steps ahead as RAW u16; GroupNorm reduce via DPP.
__global__ __launch_bounds__(512, 2) void k_scan(
    const u16* __restrict__ pre,      // f16 [4][Sc][B][D]
    const float* __restrict__ rg,
    const float* __restrict__ gnw,
    u16* __restrict__ ybuf,           // bf16 [B][S][D]
    float* __restrict__ st, int s0, int Sc)
{
  const int t   = threadIdx.x;
  const int hh  = blockIdx.y;
  const int bg0 = blockIdx.x * 2;
  const int w   = t >> 6;
  const int l   = t & 63;
  const int g   = w >> 1;
  const int ch  = w & 1;
  const int la  = l >> 4, lb = l & 15;

  __shared__ __align__(16) char  hA[16*256];     // f16 [16][128] (rows 0-1 live), swizzled 16B slots
  __shared__ __align__(16) float recl[16*132];   // [g*4+row][132]
  __shared__ float red[2][2][2];                 // [pb][wh][{sum,sq}]

  // ---- R fragments (f16) in registers ----
  f16x8 Rf[4][4];
  {
    const float* rbase = rg + ((size_t)(g*NH_ + hh)*DH_)*DH_ + ch*64;
    #pragma unroll
    for (int ct=0; ct<4; ++ct)
      #pragma unroll
      for (int ks=0; ks<4; ++ks){
        f16x8 f;
        #pragma unroll
        for (int j=0;j<8;j++)
          f[j] = (f16)rbase[(size_t)(ks*32 + la*8 + j)*DH_ + ct*16 + lb];
        Rf[ct][ks] = f;
      }
  }

  // ---- pointwise mapping & state (valid for pb<2) ----
  const int pb  = t >> 7;           // 0..3; 0..1 active
  const int col = t & 127;
  const int wh  = (t >> 6) & 1;
  const bool act = (pb < 2);
  const int pbc = act ? pb : 0;
  const int SCMP = B_*NH_*DH_;
  const int is  = ((bg0+pbc)*NH_ + hh)*128 + col;

  for (int i = t; i < 16*128; i += 512) ((u16*)hA)[i] = 0;   // clear unused rows
  float hst=0.f, cst=0.f, nst=0.f, mst=0.f;
  if (act){
    hst = st[0*SCMP + is];
    cst = st[1*SCMP + is];
    nst = st[2*SCMP + is];
    mst = st[3*SCMP + is];
    const int slot = col >> 3;
    *(u16*)&hA[pb*256 + (((slot^pb)&15)<<4) + (col&7)*2] = __builtin_bit_cast(u16, (f16)hst);
  }
  const float gws = gnw[hh*128 + col];
  const u16* prebase = pre + (size_t)(bg0+pbc)*D_ + hh*128 + col;
  const size_t gstride = (size_t)Sc*B_*D_;
  const size_t sstride = (size_t)B_*D_;
  u16 pc16[4]={0,0,0,0}, pn16[4]={0,0,0,0};
  if (act){
    #pragma unroll
    for (int g2=0; g2<4; ++g2)
      pc16[g2] = prebase[g2*gstride];
    const int s1c = (Sc > 1) ? 1 : 0;
    #pragma unroll
    for (int g2=0; g2<4; ++g2)
      pn16[g2] = prebase[g2*gstride + (size_t)s1c*sstride];
  }
  __syncthreads();

  for (int sl=0; sl<Sc; ++sl){
    // ---- prefetch step sl+2 as raw u16 (no cvt -> no vmcnt drain here) ----
    u16 pl16[4]={0,0,0,0};
    if (act){
      const int sn = (sl+2 < Sc) ? sl+2 : Sc-1;
      #pragma unroll
      for (int g2=0; g2<4; ++g2)
        pl16[g2] = prebase[g2*gstride + (size_t)sn*sstride];
    }

    // ---- Phase A: rec = h @ R via MFMA (two independent 2-deep chains) ----
    f32x4 accA[4], accB[4];
    #pragma unroll
    for (int ct=0; ct<4; ++ct){ accA[ct] = (f32x4)0.f; accB[ct] = (f32x4)0.f; }
    #pragma unroll
    for (int ks=0; ks<4; ++ks){
      const int slot = ks*4 + la;
      f16x8 af = *(const f16x8*)&hA[lb*256 + (((slot ^ lb)&15)<<4)];
      if (ks < 2){
        #pragma unroll
        for (int ct=0; ct<4; ++ct) accA[ct] = mfma16h(af, Rf[ct][ks], accA[ct]);
      } else {
        #pragma unroll
        for (int ct=0; ct<4; ++ct) accB[ct] = mfma16h(af, Rf[ct][ks], accB[ct]);
      }
    }
    if (la == 0){
      #pragma unroll
      for (int ct=0; ct<4; ++ct){
        recl[(g*4 + 0)*132 + ch*64 + ct*16 + lb] = accA[ct][0] + accB[ct][0];
        recl[(g*4 + 1)*132 + ch*64 + ct*16 + lb] = accA[ct][1] + accB[ct][1];
      }
    }
    bar_lgkm();

    // ---- Phase B: pointwise, 1 col/thread, waves 0-3 ----
    float hv = 0.f;
    if (act){
      const float iraw = (float)__builtin_bit_cast(f16, pc16[0]) + recl[(0*4+pb)*132 + col];
      const float fraw = (float)__builtin_bit_cast(f16, pc16[1]) + recl[(1*4+pb)*132 + col];
      const float zraw = (float)__builtin_bit_cast(f16, pc16[2]) + recl[(2*4+pb)*132 + col];
      const float oraw = (float)__builtin_bit_cast(f16, pc16[3]) + recl[(3*4+pb)*132 + col];
      const float lf   = mst + logsig_fast(fraw);
      const float mn   = fmaxf(iraw, lf);
      const float ig   = __expf(iraw - mn);
      const float fg   = __expf(lf - mn);
      cst = fg*cst + ig*tanh_fast(zraw);
      nst = fg*nst + ig;
      mst = mn;
      hv = sigmoid_fast(oraw) * cst * frcp(nst);
      hst = hv;
      const int slot = col >> 3;
      *(u16*)&hA[pb*256 + (((slot^pb)&15)<<4) + (col&7)*2] = __builtin_bit_cast(u16, (f16)hv);
      const float s1 = wave_sum64(hv);
      const float s2 = wave_sum64(hv*hv);
      if (l == 0){ red[pb][wh][0] = s1; red[pb][wh][1] = s2; }
    }
    bar_lgkm();

    // ---- tail: GroupNorm + y store (overlaps next step's Phase A) ----
    if (act){
      const float sum = red[pb][0][0] + red[pb][1][0];
      const float sq  = red[pb][0][1] + red[pb][1][1];
      const float mu  = sum * (1.f/128.f);
      const float var = sq * (1.f/128.f) - mu*mu;
      const float y   = (hv - mu) * rsqrtf(var + 1e-5f) * gws;
      ybuf[((size_t)(bg0+pb)*S_ + (s0+sl))*D_ + hh*128 + col] = f2bf(y);
      pc16[0]=pn16[0]; pc16[1]=pn16[1]; pc16[2]=pn16[2]; pc16[3]=pn16[3];
      pn16[0]=pl16[0]; pn16[1]=pl16[1]; pn16[2]=pl16[2]; pn16[3]=pl16[3];
    }
  }
  if (act){
    st[0*SCMP + is] = hst;
    st[1*SCMP + is] = cst;
    st[2*SCMP + is] = nst;
    st[3*SCMP + is] = mst;
  }
}

// ---------------- final: post-LN(last token) -> fc1+relu -> fc2 ----------------
__global__ __launch_bounds__(256) void k_head(const float* __restrict__ h,
     const float* __restrict__ pw, const float* __restrict__ f1w, const float* __restrict__ f1b,
     const float* __restrict__ f2w, const float* __restrict__ f2bias, float* __restrict__ out)
{
  const int b = blockIdx.x, tid = threadIdx.x;
  __shared__ float nrm[512];
  __shared__ float a1[256];
  __shared__ float red[4][2];
  const float* row = h + ((size_t)b*S_ + (S_-1))*D_;
  const float v0 = row[tid], v1 = row[tid+256];
  float s = v0+v1, q = v0*v0+v1*v1;
  #pragma unroll
  for (int off=32; off; off>>=1){ s += __shfl_down(s,off,64); q += __shfl_down(q,off,64); }
  if ((tid&63)==0){ red[tid>>6][0]=s; red[tid>>6][1]=q; }
  __syncthreads();
  const float sum = red[0][0]+red[1][0]+red[2][0]+red[3][0];
  const float sq  = red[0][1]+red[1][1]+red[2][1]+red[3][1];
  const float mu  = sum*(1.f/D_), var = sq*(1.f/D_) - mu*mu;
  const float inv = rsqrtf(var+1e-5f);
  nrm[tid]      = (v0-mu)*inv*pw[tid];
  nrm[tid+256]  = (v1-mu)*inv*pw[tid+256];
  __syncthreads();
  float acc = f1b[tid];
  for (int d=0; d<D_; ++d) acc += nrm[d]*f1w[(size_t)d*256 + tid];
  a1[tid] = fmaxf(acc, 0.f);
  __syncthreads();
  if (tid < FD_){
    float o = f2bias[tid];
    for (int i=0;i<256;++i) o += a1[i]*f2w[(size_t)i*FD_ + tid];
    out[b*FD_ + tid] = o;
  }
}

// ---------------- launcher ----------------
extern "C" void kernel_launch(void* const* d_in, const int* in_sizes, int n_in,
                              void* d_out, int out_size, void* d_ws, size_t ws_size,
                              hipStream_t stream)
{
  const float* x       = (const float*)d_in[0];
  const float* w_in    = (const float*)d_in[1];
  const float* b_in    = (const float*)d_in[2];
  const float* ln1_w   = (const float*)d_in[3];
  const float* conv_w  = (const float*)d_in[4];
  const float* conv_b  = (const float*)d_in[5];
  const float* w_gates = (const float*)d_in[6];
  const float* r_gates = (const float*)d_in[7];
  const float* b_gates = (const float*)d_in[8];
  const float* gn_w    = (const float*)d_in[9];
  const float* ln2_w   = (const float*)d_in[10];
  const float* ff_up   = (const float*)d_in[11];
  const float* ff_down = (const float*)d_in[12];
  const float* post_ln = (const float*)d_in[13];
  const float* fc1_w   = (const float*)d_in[14];
  const float* fc1_b   = (const float*)d_in[15];
  const float* fc2_w   = (const float*)d_in[16];
  const float* fc2_b   = (const float*)d_in[17];
  float* out = (float*)d_out;

  // ---- persistent workspace layout (bytes) ----
  char* ws = (char*)d_ws;
  const size_t OFF_H     = 0;           // f32 h           52,428,800
  const size_t OFF_XNBF  = 52428800;    // bf16 xn/xn2     26,214,400
  const size_t OFF_WGBF  = 78643200;    // bf16 w_gates     1,048,576
  const size_t OFF_UPBF  = 79691776;    // bf16 ff_up       2,883,584
  const size_t OFF_DNBF  = 82575360;    // bf16 ff_down     1,441,792
  const size_t OFF_STATE = 84017152;    // f32 scan state   1,048,576
  const size_t OFF_YBUF  = 85065728;    // bf16 y          26,214,400
  const size_t OFF_CHUNK = 111280128;   // chunked region (rest)

  // per-s chunk cost: pre f16 (524,288) + xc bf16 (131,072)
  if (ws_size < OFF_CHUNK + 655360ull){
    k_sentinel<<<4, 256, 0, stream>>>(out, out_size);
    return;
  }
  const size_t CR = ws_size - OFF_CHUNK;
  int Sc = (int)(CR / 655360ull); if (Sc > S_) Sc = S_;
  // per-M-row cost for FFN phase: act bf16 (UP*2 = 1408)
  int Mc = (int)((CR / 1408ull) & ~(size_t)127); if (Mc > M_) Mc = M_;

  float* h     = (float*)(ws + OFF_H);
  u16*   xnbf  = (u16*)  (ws + OFF_XNBF);
  u16*   wgbf  = (u16*)  (ws + OFF_WGBF);
  u16*   upbf  = (u16*)  (ws + OFF_UPBF);
  u16*   dnbf  = (u16*)  (ws + OFF_DNBF);
  float* st    = (float*)(ws + OFF_STATE);
  u16*   ybuf  = (u16*)  (ws + OFF_YBUF);
  u16*   xcc   = (u16*)  (ws + OFF_CHUNK);
  u16*   prec  = (u16*)  (ws + OFF_CHUNK + (size_t)Sc*131072);
  u16*   actc  = (u16*)  (ws + OFF_CHUNK);    // aliases xcc/prec (disjoint in time)

  // cast + pack weights to bf16 fragment order (one-time)
  {
    int n1 = NB_*4*NH_*DH_*DH_;  k_cast_pack_gates<<<(n1+255)/256, 256, 0, stream>>>(w_gates, wgbf, n1);
    int n2 = NB_*D_*2*UP_;       k_cast_pack_up<<<(n2+255)/256, 256, 0, stream>>>(ff_up, upbf, n2);
    int n3 = NB_*UP_*D_;         k_cast_pack_dn<<<(n3+255)/256, 256, 0, stream>>>(ff_down, dnbf, n3);
  }

  k_inproj<<<M_/8, 256, 0, stream>>>(x, w_in, b_in, h);

  for (int blk=0; blk<NB_; ++blk){
    k_ln<<<M_, 128, 0, stream>>>(h, ln1_w + blk*D_, xnbf);
    k_zero<<<1024, 256, 0, stream>>>(st, 4*B_*NH_*DH_);
    for (int s0=0; s0<S_; s0+=Sc){
      const int scur = (S_ - s0 < Sc) ? (S_ - s0) : Sc;
      k_conv<<<scur*64, 256, 0, stream>>>(xnbf, conv_w + blk*KK_*D_, conv_b + blk*D_,
                                          xcc, s0, scur);
      dim3 gg((B_*scur)/128, 16);
      k_gemm_gates<<<gg, 256, 0, stream>>>(xcc, xnbf,
          wgbf + (size_t)blk*4*NH_*DH_*DH_, b_gates + (size_t)blk*4*D_, prec, s0, scur);
      dim3 gs(B_/2, NH_);
      k_scan<<<gs, 512, 0, stream>>>(prec, r_gates + (size_t)blk*4*NH_*DH_*DH_,
                                     gn_w + blk*D_, ybuf, st, s0, scur);
    }
    // h += y ; LN2 -> bf16
    k_addln<<<M_, 128, 0, stream>>>(h, ybuf, ln2_w + blk*D_, xnbf);
    // M-chunked FFN: up+GLU fused -> act(bf16); down += into h
    for (int m0c=0; m0c<M_; m0c+=Mc){
      const int mcur = (M_ - m0c < Mc) ? (M_ - m0c) : Mc;
      dim3 g1(mcur/128, (2*UP_)/128);   // 11 n-blocks
      k_gemm_up<<<g1, 256, 0, stream>>>(xnbf + (size_t)m0c*D_,
                                        upbf + (size_t)blk*D_*2*UP_, actc);
      dim3 g2(mcur/128, D_/128);        // 4 n-blocks
      k_gemm_ffn<<<g2, 256, 0, stream>>>(actc, UP_,
                                         dnbf + (size_t)blk*UP_*D_, D_,
                                         h + (size_t)m0c*D_, D_, UP_, 1);
    }
  }

  k_head<<<B_, 256, 0, stream>>>(h, post_ln, fc1_w, fc1_b, fc2_w, fc2_b, out);
}